// Round 5
// baseline (9762.981 us; speedup 1.0000x reference)
//
#include <hip/hip_runtime.h>

// CAGenerator: 64-step neural CA — weight-stationary 2-phase persistent kernel.
// Folded weights: Wc = W2@W1 (512x720), bc = W2@b1+b2 (no relu between them).
// mask = uniform()<1.0 always true -> no RNG.
// 256 WGs x 256 thr, 1 WG/CU, persistent, 2 grid barriers/step.
//   WG g: mi = g>>5 (64 H-channels), ni = g&31 (img b=ni>>2, rows yb=(ni&3)*8..+8)
//   Phase A: live mask -> masked state LDS tile -> gemm1 (Wc in REGISTERS,
//            B-frags = single ds_read_b128 from LDS via permuted-K im2col)
//            -> H chunks to global (fragment-ready layout).  [barrier]
//   Phase B: WG owns row y_own = yb+mi: upd = W3*H (K split across waves,
//            LDS reduce); U = masked_state + upd + b3.      [barrier]
// K-permutation: k = tap*80 + ci, so each 8-elem fragment run = 8 consecutive
// channels at one (dy,dx) tap. K=720 = 45*16 exactly (no padding).

#define NPIX 8192
#define T_ALIVE 0.01f
#define NBLK 256

typedef _Float16 f16;
typedef __attribute__((ext_vector_type(8)))  _Float16 h8_t;
typedef __attribute__((ext_vector_type(4)))  _Float16 h4_t;
typedef __attribute__((ext_vector_type(16))) float    fx16;

// ---------------------------------------------------------------------------
// Prep kernels
// ---------------------------------------------------------------------------
__global__ __launch_bounds__(256) void wc_gemm(
    const float* __restrict__ W1, const float* __restrict__ W2,
    float* __restrict__ Wc)
{
    const int k = blockIdx.x * 256 + threadIdx.x;
    const int by = blockIdx.y;
    if (k >= 720) return;
    float a0 = 0.f, a1 = 0.f, a2 = 0.f, a3 = 0.f;
    for (int h = 0; h < 512; ++h) {
        const float w1v = W1[h * 720 + k];
        a0 += W2[(by      ) * 512 + h] * w1v;
        a1 += W2[(by + 128) * 512 + h] * w1v;
        a2 += W2[(by + 256) * 512 + h] * w1v;
        a3 += W2[(by + 384) * 512 + h] * w1v;
    }
    Wc[(size_t)(by      ) * 720 + k] = a0;
    Wc[(size_t)(by + 128) * 720 + k] = a1;
    Wc[(size_t)(by + 256) * 720 + k] = a2;
    Wc[(size_t)(by + 384) * 720 + k] = a3;
}

__global__ __launch_bounds__(256) void bc_k(
    const float* __restrict__ W2, const float* __restrict__ b1,
    const float* __restrict__ b2, float* __restrict__ bc)
{
    const int m = blockIdx.x * 256 + threadIdx.x;
    if (m >= 512) return;
    float a = b2[m];
    for (int h = 0; h < 512; ++h) a += W2[m * 512 + h] * b1[h];
    bc[m] = a;
}

// Wcsw2: 32x32x16 A-frags, K permuted (kp = tap*80+ci).
// Wcsw2[((ks*16 + mtg)*64 + lane)*8 + j] = Wc[mtg*32+(lane&31)][ci*9+tap]
__global__ __launch_bounds__(256) void swz_wc2(
    const float* __restrict__ Wc, f16* __restrict__ Wcsw2)
{
    const int idx = blockIdx.x * 256 + threadIdx.x;
    if (idx >= 45 * 16 * 64) return;
    const int lane = idx & 63;
    const int t = idx >> 6;
    const int mtg = t & 15, ks = t >> 4;
    const int m = mtg * 32 + (lane & 31);
    const int k0 = ks * 16 + (lane >> 5) * 8;
    h8_t v;
#pragma unroll
    for (int j = 0; j < 8; ++j) {
        const int kp = k0 + j;
        const int tap = kp / 80, ci = kp - tap * 80;
        v[j] = (f16)Wc[(size_t)m * 720 + ci * 9 + tap];
    }
    *(h8_t*)(Wcsw2 + (size_t)idx * 8) = v;
}

// W3sw2: 32x32x16 A-frags for W3 (80x512 padded to 96).
__global__ __launch_bounds__(256) void swz_w32(
    const float* __restrict__ W3, f16* __restrict__ W3sw2)
{
    const int idx = blockIdx.x * 256 + threadIdx.x;
    if (idx >= 32 * 3 * 64) return;
    const int lane = idx & 63;
    const int t = idx >> 6;
    const int mt = t % 3, ks2 = t / 3;
    const int m = mt * 32 + (lane & 31);
    const int k0 = ks2 * 16 + (lane >> 5) * 8;
    h8_t v;
#pragma unroll
    for (int j = 0; j < 8; ++j)
        v[j] = (f16)((m < 80) ? W3[(size_t)m * 512 + k0 + j] : 0.f);
    *(h8_t*)(W3sw2 + (size_t)idx * 8) = v;
}

// ---------------------------------------------------------------------------
// Grid barrier (epoch-based, proven in R4)
// ---------------------------------------------------------------------------
__device__ inline void gbar(int* cnt, int* flag, int ep)
{
    __syncthreads();
    if (threadIdx.x == 0) {
        __threadfence();
        if (__hip_atomic_fetch_add(cnt, 1, __ATOMIC_ACQ_REL,
                                   __HIP_MEMORY_SCOPE_AGENT) == NBLK - 1) {
            __hip_atomic_store(cnt, 0, __ATOMIC_RELAXED,
                               __HIP_MEMORY_SCOPE_AGENT);
            __hip_atomic_store(flag, ep, __ATOMIC_RELEASE,
                               __HIP_MEMORY_SCOPE_AGENT);
        } else {
            while (__hip_atomic_load(flag, __ATOMIC_ACQUIRE,
                                     __HIP_MEMORY_SCOPE_AGENT) < ep)
                __builtin_amdgcn_s_sleep(1);
        }
        __threadfence();
    }
    __syncthreads();
}

// ---------------------------------------------------------------------------
// Persistent 2-phase CA kernel
// ---------------------------------------------------------------------------
__global__ __launch_bounds__(256, 1) void ca2(
    const float* __restrict__ z,   const float* __restrict__ b3g,
    const f16* __restrict__ Wcsw2, const f16* __restrict__ W3sw2,
    const float* __restrict__ bc,
    float* __restrict__ U0, float* __restrict__ U1,
    float* __restrict__ Ma0, float* __restrict__ Ma1,
    f16* __restrict__ Hg,
    float* __restrict__ dout, int* __restrict__ bar)
{
    __shared__ __align__(16) char smem[56256];
    f16*   msT2  = (f16*)smem;               // 10 cc x 340 px x 8 = 54400 B
    float* redT  = (float*)smem;             // phase-B reduce, 49152 B (reuse)
    float* livef = (float*)(smem + 54400);   // 320 floats
    float* bcL   = (float*)(smem + 55680);   // 64 floats
    float* b3L   = (float*)(smem + 55936);   // 80 floats

    const int tid = threadIdx.x;
    const int lane = tid & 63, w = tid >> 6;
    const int li = lane & 31, q2 = lane >> 5;
    const int g = blockIdx.x;
    const int mi = g >> 5, ni = g & 31;
    const int b = ni >> 2, yb = (ni & 3) * 8;
    const int gb = b * 1024;
    int* cnt = bar; int* flag = bar + 1;

    // resident A-fragments (Wc slice) in registers: 45 x h8 = 180 VGPR
    h8_t a[45];
    const int mtg = mi * 2 + (w & 1);
#pragma unroll
    for (int ks = 0; ks < 45; ++ks)
        a[ks] = *(const h8_t*)(Wcsw2 + (((size_t)ks * 16 + mtg) * 64 + lane) * 8);
    if (tid < 64) bcL[tid] = bc[mi * 64 + tid];
    if (tid < 80) b3L[tid] = b3g[tid];
    __syncthreads();

    for (int s = 0; s <= 64; ++s) {
        const float* Uprev = (s & 1) ? U0 : U1;
        float*       Ucur  = (s & 1) ? U1 : U0;
        const float* MaPrv = (s & 1) ? Ma0 : Ma1;
        float*       MaCur = (s & 1) ? Ma1 : Ma0;

        // ---------------- live mask (10 halo rows x 32) -------------------
        for (int p = tid; p < 320; p += 256) {
            float lv;
            if (s == 0) lv = 1.f;
            else {
                const int hrow = p >> 5, x = p & 31, y = yb - 1 + hrow;
                lv = 0.f;
                if ((unsigned)y < 32u) {
                    float post = -1e30f, pre = -1e30f;
                    for (int dy = -1; dy <= 1; ++dy) {
                        const int yy = y + dy;
                        if ((unsigned)yy >= 32u) continue;
                        for (int dx = -1; dx <= 1; ++dx) {
                            const int xx = x + dx;
                            if ((unsigned)xx >= 32u) continue;
                            post = fmaxf(post, Uprev[gb + yy * 32 + xx]);
                            pre  = fmaxf(pre,  MaPrv[gb + yy * 32 + xx]);
                        }
                    }
                    lv = (post > T_ALIVE && pre > T_ALIVE) ? 1.f : 0.f;
                }
            }
            livef[p] = lv;
        }
        __syncthreads();

        if (s == 64) {   // final masked alpha -> output (mi==0 WGs)
            if (mi == 0) {
                const int hrow = (tid >> 5) + 1, x = tid & 31;
                const int y = yb + (tid >> 5);
                dout[gb + y * 32 + x] =
                    Uprev[gb + y * 32 + x] * livef[hrow * 32 + x];
            }
            break;
        }

        // ------------- masked-state LDS tile (fp16) + Ma write ------------
        for (int idx = tid; idx < 3400; idx += 256) {
            const int cc = idx / 340, px = idx - cc * 340;
            const int hrow = px / 34, xi = px - hrow * 34;
            const int gx = xi - 1, y = yb - 1 + hrow;
            const bool inb = ((unsigned)y < 32u) & ((unsigned)gx < 32u);
            const float lv = inb ? livef[hrow * 32 + (gx & 31)] : 0.f;
            h8_t v;
#pragma unroll
            for (int j = 0; j < 8; ++j) {
                float fv = 0.f;
                if (inb) {
                    const int c = cc * 8 + j;
                    if (s == 0)
                        fv = (y == 16 && gx == 16)
                             ? (c ? z[b * 100 + c - 1] : 1.f) : 0.f;
                    else
                        fv = Uprev[(size_t)c * NPIX + gb + y * 32 + gx] * lv;
                }
                v[j] = (f16)fv;
            }
            *(h8_t*)(msT2 + (size_t)idx * 8) = v;
        }
        if (mi == 0) {
            const int hrow = (tid >> 5) + 1, x = tid & 31;
            const int y = yb + (tid >> 5);
            float av;
            if (s == 0) av = (y == 16 && x == 16) ? 1.f : 0.f;
            else av = Uprev[gb + y * 32 + x] * livef[hrow * 32 + x];
            MaCur[gb + y * 32 + x] = av;
        }
        __syncthreads();

        // ---------------- phase A: gemm1 (Wc x im2col) --------------------
        fx16 acc[4];
#pragma unroll
        for (int j4 = 0; j4 < 4; ++j4)
#pragma unroll
            for (int r = 0; r < 16; ++r) acc[j4][r] = 0.f;

#pragma unroll
        for (int ks = 0; ks < 45; ++ks) {
            const int i80 = 2 * ks, i81 = 2 * ks + 1;
            const int tap0 = i80 / 10, tap1 = i81 / 10;
            const int cc0 = i80 - tap0 * 10, cc1 = i81 - tap1 * 10;
            const int dy0 = tap0 / 3 - 1, dx0 = tap0 % 3 - 1;
            const int dy1 = tap1 / 3 - 1, dx1 = tap1 % 3 - 1;
            const int dy = q2 ? dy1 : dy0;
            const int dx = q2 ? dx1 : dx0;
            const int cc = q2 ? cc1 : cc0;
            h8_t bf[4];
#pragma unroll
            for (int j4 = 0; j4 < 4; ++j4) {
                const int ntg = (w >> 1) * 4 + j4;
                const int px = (ntg + 1 + dy) * 34 + (li + dx + 1);
                bf[j4] = *(const h8_t*)(msT2 + (size_t)(cc * 340 + px) * 8);
            }
#pragma unroll
            for (int j4 = 0; j4 < 4; ++j4)
                acc[j4] = __builtin_amdgcn_mfma_f32_32x32x16_f16(
                    a[ks], bf[j4], acc[j4], 0, 0, 0);
        }

        // H epilogue: relu(acc+bc) -> Hg[(ch>>2)][n][4] (fragment-ready)
#pragma unroll
        for (int j4 = 0; j4 < 4; ++j4) {
            const int ntg = (w >> 1) * 4 + j4;
            const size_t ng = gb + (yb + ntg) * 32 + li;
#pragma unroll
            for (int aa = 0; aa < 4; ++aa) {
                const int chl = (w & 1) * 32 + 8 * aa + 4 * q2;
                h4_t v4;
#pragma unroll
                for (int rb = 0; rb < 4; ++rb)
                    v4[rb] = (f16)fmaxf(acc[j4][aa * 4 + rb] + bcL[chl + rb], 0.f);
                const int cg = mi * 16 + (w & 1) * 8 + 2 * aa + q2;
                *(h4_t*)(Hg + ((size_t)cg * NPIX + ng) * 4) = v4;
            }
        }

        gbar(cnt, flag, 2 * s + 1);

        // ---------------- phase B: upd = W3*H, state update ---------------
        const int y_own = yb + mi;
        const size_t nbg = gb + y_own * 32 + li;
        fx16 acc3[3];
#pragma unroll
        for (int mt = 0; mt < 3; ++mt)
#pragma unroll
            for (int r = 0; r < 16; ++r) acc3[mt][r] = 0.f;

#pragma unroll
        for (int k2 = 0; k2 < 8; ++k2) {
            const int ks2 = w * 8 + k2;
            const int cg0 = ks2 * 4 + q2 * 2;
            const h4_t h0 = *(const h4_t*)(Hg + ((size_t)cg0 * NPIX + nbg) * 4);
            const h4_t h1 = *(const h4_t*)(Hg + ((size_t)(cg0 + 1) * NPIX + nbg) * 4);
            h8_t bf;
#pragma unroll
            for (int j = 0; j < 4; ++j) { bf[j] = h0[j]; bf[4 + j] = h1[j]; }
#pragma unroll
            for (int mt = 0; mt < 3; ++mt) {
                const h8_t w3f = *(const h8_t*)(W3sw2 +
                    (((size_t)ks2 * 3 + mt) * 64 + lane) * 8);
                acc3[mt] = __builtin_amdgcn_mfma_f32_32x32x16_f16(
                    w3f, bf, acc3[mt], 0, 0, 0);
            }
        }
        // cross-wave K reduction via LDS (conflict-free float4 layout)
#pragma unroll
        for (int mt = 0; mt < 3; ++mt)
#pragma unroll
            for (int aa = 0; aa < 4; ++aa) {
                float4 v;
                v.x = acc3[mt][aa * 4 + 0]; v.y = acc3[mt][aa * 4 + 1];
                v.z = acc3[mt][aa * 4 + 2]; v.w = acc3[mt][aa * 4 + 3];
                *(float4*)(redT + (((w * 3 + mt) * 4 + aa) * 256 + lane * 4)) = v;
            }
        __syncthreads();
        if (w < 3) {
            const int mt = w;
            const float lv = livef[(mi + 1) * 32 + li];
#pragma unroll
            for (int aa = 0; aa < 4; ++aa) {
                float4 s0 = *(float4*)(redT + (((0 * 3 + mt) * 4 + aa) * 256 + lane * 4));
                float4 s1 = *(float4*)(redT + (((1 * 3 + mt) * 4 + aa) * 256 + lane * 4));
                float4 s2 = *(float4*)(redT + (((2 * 3 + mt) * 4 + aa) * 256 + lane * 4));
                float4 s3 = *(float4*)(redT + (((3 * 3 + mt) * 4 + aa) * 256 + lane * 4));
                float t4[4] = {s0.x + s1.x + s2.x + s3.x,
                               s0.y + s1.y + s2.y + s3.y,
                               s0.z + s1.z + s2.z + s3.z,
                               s0.w + s1.w + s2.w + s3.w};
#pragma unroll
                for (int rb = 0; rb < 4; ++rb) {
                    const int c = mt * 32 + rb + 8 * aa + 4 * q2;
                    if (c < 80) {
                        const size_t idx = (size_t)c * NPIX + nbg;
                        float base;
                        if (s == 0)
                            base = (y_own == 16 && li == 16)
                                   ? (c ? z[b * 100 + c - 1] : 1.f) : 0.f;
                        else
                            base = Uprev[idx] * lv;
                        Ucur[idx] = base + t4[rb] + b3L[c];
                    }
                }
            }
        }

        gbar(cnt, flag, 2 * s + 2);
    }
}

// ---------------------------------------------------------------------------
extern "C" void kernel_launch(void* const* d_in, const int* in_sizes, int n_in,
                              void* d_out, int out_size, void* d_ws, size_t ws_size,
                              hipStream_t stream)
{
    const float* z  = (const float*)d_in[0];
    const float* W1 = (const float*)d_in[1];   // 512 x 720
    const float* b1 = (const float*)d_in[2];
    const float* W2 = (const float*)d_in[3];   // 512 x 512
    const float* b2 = (const float*)d_in[4];
    const float* W3 = (const float*)d_in[5];   // 80 x 512
    const float* b3 = (const float*)d_in[6];

    char* ws = (char*)d_ws;
    float* U0    = (float*)ws;  ws += (size_t)80 * NPIX * 4;
    float* U1    = (float*)ws;  ws += (size_t)80 * NPIX * 4;
    float* Ma0   = (float*)ws;  ws += NPIX * 4;
    float* Ma1   = (float*)ws;  ws += NPIX * 4;
    float* bc    = (float*)ws;  ws += 512 * 4;
    float* Wc    = (float*)ws;  ws += (size_t)512 * 720 * 4;
    f16*   Wcsw2 = (f16*)ws;   ws += (size_t)45 * 16 * 64 * 8 * 2;
    f16*   W3sw2 = (f16*)ws;   ws += (size_t)32 * 3 * 64 * 8 * 2;
    f16*   Hg    = (f16*)ws;   ws += (size_t)128 * NPIX * 4 * 2;   // 8 MB
    int*   bar   = (int*)ws;   ws += 16;

    hipMemsetAsync(bar, 0, 8, stream);
    wc_gemm<<<dim3(3, 128), 256, 0, stream>>>(W1, W2, Wc);
    bc_k<<<2, 256, 0, stream>>>(W2, b1, b2, bc);
    swz_wc2<<<180, 256, 0, stream>>>(Wc, Wcsw2);
    swz_w32<<<24, 256, 0, stream>>>(W3, W3sw2);

    ca2<<<NBLK, 256, 0, stream>>>(z, b3, Wcsw2, W3sw2, bc,
                                  U0, U1, Ma0, Ma1, Hg,
                                  (float*)d_out, bar);
}

// Round 6
// 7462.186 us; speedup vs baseline: 1.3083x; 1.3083x over previous
//
#include <hip/hip_runtime.h>

// CAGenerator: 64-step neural CA — single persistent kernel, N-ownership.
// Folded: Wc = W2@W1 (512x720), bc = W2@b1+b2 (no relu between conv3x3 and
// first 1x1). mask = uniform()<1.0 always true -> no RNG.
// 256 WGs x 256 thr (1/CU), WG g owns row y0 = g&31 of image b = g>>5.
// Per step, per WG (NO cross-WG activation traffic):
//   livef (3 halo rows) -> masked state msT in LDS (fp16, channel-octet) ->
//   gemm1: ALL 512 H for own 32 px (Wc streamed, depth-4 reg prefetch;
//          B-frags = one ds_read_b128 via permuted-K im2col) -> H in LDS ->
//   gemm3: upd = W3*H (W3 REGISTER-RESIDENT, K split 4 waves, LDS reduce) ->
//   U/Ma epilogue -> flag-array grid barrier (1/step).
// K-permutation kp = tap*80 + ci: 8-elem fragment run = 8 consecutive
// channels at one (dy,dx) tap; 720 = 45*16 exactly. 80 ch = 10 octets/tap.

#define NPIX 8192
#define T_ALIVE 0.01f
#define NBLK 256

typedef _Float16 f16;
typedef __attribute__((ext_vector_type(8)))  _Float16 h8_t;
typedef __attribute__((ext_vector_type(4)))  _Float16 h4_t;
typedef __attribute__((ext_vector_type(16))) float    fx16;

// ---------------------------------------------------------------------------
// Prep kernels (verified R5)
// ---------------------------------------------------------------------------
__global__ __launch_bounds__(256) void wc_gemm(
    const float* __restrict__ W1, const float* __restrict__ W2,
    float* __restrict__ Wc)
{
    const int k = blockIdx.x * 256 + threadIdx.x;
    const int by = blockIdx.y;
    if (k >= 720) return;
    float a0 = 0.f, a1 = 0.f, a2 = 0.f, a3 = 0.f;
    for (int h = 0; h < 512; ++h) {
        const float w1v = W1[h * 720 + k];
        a0 += W2[(by      ) * 512 + h] * w1v;
        a1 += W2[(by + 128) * 512 + h] * w1v;
        a2 += W2[(by + 256) * 512 + h] * w1v;
        a3 += W2[(by + 384) * 512 + h] * w1v;
    }
    Wc[(size_t)(by      ) * 720 + k] = a0;
    Wc[(size_t)(by + 128) * 720 + k] = a1;
    Wc[(size_t)(by + 256) * 720 + k] = a2;
    Wc[(size_t)(by + 384) * 720 + k] = a3;
}

__global__ __launch_bounds__(256) void bc_k(
    const float* __restrict__ W2, const float* __restrict__ b1,
    const float* __restrict__ b2, float* __restrict__ bc)
{
    const int m = blockIdx.x * 256 + threadIdx.x;
    if (m >= 512) return;
    float a = b2[m];
    for (int h = 0; h < 512; ++h) a += W2[m * 512 + h] * b1[h];
    bc[m] = a;
}

// 32x32x16 A-frags, K permuted (kp = tap*80+ci).
__global__ __launch_bounds__(256) void swz_wc2(
    const float* __restrict__ Wc, f16* __restrict__ Wcsw2)
{
    const int idx = blockIdx.x * 256 + threadIdx.x;
    if (idx >= 45 * 16 * 64) return;
    const int lane = idx & 63;
    const int t = idx >> 6;
    const int mtg = t & 15, ks = t >> 4;
    const int m = mtg * 32 + (lane & 31);
    const int k0 = ks * 16 + (lane >> 5) * 8;
    h8_t v;
#pragma unroll
    for (int j = 0; j < 8; ++j) {
        const int kp = k0 + j;
        const int tap = kp / 80, ci = kp - tap * 80;
        v[j] = (f16)Wc[(size_t)m * 720 + ci * 9 + tap];
    }
    *(h8_t*)(Wcsw2 + (size_t)idx * 8) = v;
}

// 32x32x16 A-frags for W3 (80x512 padded to 96).
__global__ __launch_bounds__(256) void swz_w32(
    const float* __restrict__ W3, f16* __restrict__ W3sw2)
{
    const int idx = blockIdx.x * 256 + threadIdx.x;
    if (idx >= 32 * 3 * 64) return;
    const int lane = idx & 63;
    const int t = idx >> 6;
    const int mt = t % 3, ks2 = t / 3;
    const int m = mt * 32 + (lane & 31);
    const int k0 = ks2 * 16 + (lane >> 5) * 8;
    h8_t v;
#pragma unroll
    for (int j = 0; j < 8; ++j)
        v[j] = (f16)((m < 80) ? W3[(size_t)m * 512 + k0 + j] : 0.f);
    *(h8_t*)(W3sw2 + (size_t)idx * 8) = v;
}

// ---------------------------------------------------------------------------
// Flag-array grid barrier: parallel arrivals, WG0 wave0 polls, release flag.
// ---------------------------------------------------------------------------
__device__ inline void gbar(int* flags, int* go, int ep)
{
    __syncthreads();
    if (threadIdx.x < 64) {
        if (threadIdx.x == 0) {
            __threadfence();
            __hip_atomic_store(&flags[blockIdx.x], ep, __ATOMIC_RELEASE,
                               __HIP_MEMORY_SCOPE_AGENT);
        }
        if (blockIdx.x == 0) {
            const int l = threadIdx.x;     // each lane watches 4 flags
            for (;;) {
                bool ready = true;
#pragma unroll
                for (int j = 0; j < 4; ++j)
                    ready &= (__hip_atomic_load(&flags[l * 4 + j],
                              __ATOMIC_ACQUIRE, __HIP_MEMORY_SCOPE_AGENT) >= ep);
                if (__all(ready)) break;
                __builtin_amdgcn_s_sleep(1);
            }
            if (l == 0)
                __hip_atomic_store(go, ep, __ATOMIC_RELEASE,
                                   __HIP_MEMORY_SCOPE_AGENT);
        }
        if (threadIdx.x == 0) {
            while (__hip_atomic_load(go, __ATOMIC_ACQUIRE,
                                     __HIP_MEMORY_SCOPE_AGENT) < ep)
                __builtin_amdgcn_s_sleep(1);
            __threadfence();
        }
    }
    __syncthreads();
}

// ---------------------------------------------------------------------------
// Persistent CA kernel
// ---------------------------------------------------------------------------
__global__ __launch_bounds__(256, 1) void ca3(
    const float* __restrict__ z,     const float* __restrict__ b3g,
    const f16* __restrict__ Wcsw2,   const f16* __restrict__ W3sw2,
    const float* __restrict__ bc,
    float* __restrict__ U0, float* __restrict__ U1,
    float* __restrict__ Ma0, float* __restrict__ Ma1,
    float* __restrict__ dout, int* __restrict__ bar)
{
    __shared__ __align__(16) char smem[52224];
    f16*   msT   = (f16*)smem;                 // [0,16320)  10cc x 102px x 16B
    f16*   Hsw   = (f16*)(smem + 16384);       // [16384,49152)  512x32 fp16
    float* redT  = (float*)smem;               // overlay [0,49152)
    float* bcL   = (float*)(smem + 49152);     // 512 f
    float* b3L   = (float*)(smem + 51200);     // 80 f
    float* livef = (float*)(smem + 51584);     // 96 f

    const int tid = threadIdx.x;
    const int lane = tid & 63, w = tid >> 6;
    const int li = lane & 31, q2 = lane >> 5;
    const int g = blockIdx.x;
    const int b = g >> 5, y0 = g & 31;
    const int gb = b * 1024;
    const size_t nbg = (size_t)(gb + y0 * 32 + li);
    int* flags = bar; int* go = bar + 256;

    // W3 register-resident: 24 x h8 = 96 VGPR per wave
    h8_t w3r[8][3];
#pragma unroll
    for (int k2 = 0; k2 < 8; ++k2)
#pragma unroll
        for (int mt = 0; mt < 3; ++mt)
            w3r[k2][mt] = *(const h8_t*)(W3sw2 +
                (((size_t)(w * 8 + k2) * 3 + mt) * 64 + lane) * 8);
    for (int i = tid; i < 512; i += 256) bcL[i] = bc[i];
    if (tid < 80) b3L[tid] = b3g[tid];
    // per-lane im2col plane offsets (halfs) for the 9 taps
    int pxh[9];
#pragma unroll
    for (int t = 0; t < 9; ++t)
        pxh[t] = ((t / 3) * 34 + li + (t % 3)) * 8;
    __syncthreads();

    for (int s = 0; s <= 64; ++s) {
        const float* Uprev = (s & 1) ? U0 : U1;
        float*       Ucur  = (s & 1) ? U1 : U0;
        const float* MaPrv = (s & 1) ? Ma0 : Ma1;
        float*       MaCur = (s & 1) ? Ma1 : Ma0;

        // ---------------- live mask (3 halo rows x 32) --------------------
        if (tid < 96) {
            float lv;
            if (s == 0) lv = 1.f;
            else {
                const int hrow = tid >> 5, x = tid & 31;
                const int y = y0 - 1 + hrow;
                lv = 0.f;
                if ((unsigned)y < 32u) {
                    float post = -1e30f, pre = -1e30f;
                    for (int dy = -1; dy <= 1; ++dy) {
                        const int yy = y + dy;
                        if ((unsigned)yy >= 32u) continue;
                        for (int dx = -1; dx <= 1; ++dx) {
                            const int xx = x + dx;
                            if ((unsigned)xx >= 32u) continue;
                            post = fmaxf(post, Uprev[gb + yy * 32 + xx]);
                            pre  = fmaxf(pre,  MaPrv[gb + yy * 32 + xx]);
                        }
                    }
                    lv = (post > T_ALIVE && pre > T_ALIVE) ? 1.f : 0.f;
                }
            }
            livef[tid] = lv;
        }
        __syncthreads();

        if (s == 64) {   // output: masked alpha of own row
            if (tid < 32)
                dout[gb + y0 * 32 + tid] =
                    Uprev[gb + y0 * 32 + tid] * livef[32 + tid];
            break;
        }

        // ------------- masked-state LDS tile (fp16, octet) + Ma ----------
        for (int idx = tid; idx < 1020; idx += 256) {
            const int cc = idx / 102, px = idx - cc * 102;
            const int hrow = px / 34, xi = px - hrow * 34;
            const int gx = xi - 1, y = y0 - 1 + hrow;
            const bool inb = ((unsigned)y < 32u) & ((unsigned)gx < 32u);
            h8_t v;
            if (s == 0) {
#pragma unroll
                for (int j = 0; j < 8; ++j) {
                    const int c = cc * 8 + j;
                    const float fv = (inb && y == 16 && gx == 16)
                                     ? (c ? z[b * 100 + c - 1] : 1.f) : 0.f;
                    v[j] = (f16)fv;
                }
            } else {
                const float lv = inb ? livef[hrow * 32 + gx] : 0.f;
#pragma unroll
                for (int j = 0; j < 8; ++j) {
                    float fv = 0.f;
                    if (inb)
                        fv = Uprev[(size_t)(cc * 8 + j) * NPIX + gb + y * 32 + gx] * lv;
                    v[j] = (f16)fv;
                }
            }
            *(h8_t*)(msT + (size_t)idx * 8) = v;
        }
        if (tid < 32) {
            const float av = (s == 0)
                ? ((y0 == 16 && tid == 16) ? 1.f : 0.f)
                : Uprev[gb + y0 * 32 + tid] * livef[32 + tid];
            MaCur[gb + y0 * 32 + tid] = av;
        }
        __syncthreads();

        // ---------------- gemm1: all 512 H for own 32 px ------------------
        fx16 acc[4];
#pragma unroll
        for (int i = 0; i < 4; ++i)
#pragma unroll
            for (int r = 0; r < 16; ++r) acc[i][r] = 0.f;

        h8_t abuf[4][4];   // depth-4 prefetch ring
#pragma unroll
        for (int pk = 0; pk < 4; ++pk)
#pragma unroll
            for (int i = 0; i < 4; ++i)
                abuf[pk][i] = *(const h8_t*)(Wcsw2 +
                    (((size_t)pk * 16 + (w * 4 + i)) * 64 + lane) * 8);

#pragma unroll
        for (int ks = 0; ks < 45; ++ks) {
            const int o0 = 2 * ks, o1 = 2 * ks + 1;
            const int a0 = (o0 % 10) * 816 + pxh[o0 / 10];
            const int a1 = (o1 % 10) * 816 + pxh[o1 / 10];
            const h8_t bf = *(const h8_t*)(msT + (q2 ? a1 : a0));
            h8_t av[4];
#pragma unroll
            for (int i = 0; i < 4; ++i) av[i] = abuf[ks & 3][i];
            if (ks + 4 < 45) {
#pragma unroll
                for (int i = 0; i < 4; ++i)
                    abuf[ks & 3][i] = *(const h8_t*)(Wcsw2 +
                        (((size_t)(ks + 4) * 16 + (w * 4 + i)) * 64 + lane) * 8);
            }
#pragma unroll
            for (int i = 0; i < 4; ++i)
                acc[i] = __builtin_amdgcn_mfma_f32_32x32x16_f16(
                    av[i], bf, acc[i], 0, 0, 0);
        }

        // H epilogue: relu(acc+bc) -> Hsw (gemm3-fragment-ready)
#pragma unroll
        for (int i = 0; i < 4; ++i) {
            const int t = w * 4 + i;
#pragma unroll
            for (int aa = 0; aa < 4; ++aa) {
                const int m0 = t * 32 + 8 * aa + 4 * q2;
                h4_t v4;
#pragma unroll
                for (int rb = 0; rb < 4; ++rb)
                    v4[rb] = (f16)fmaxf(acc[i][aa * 4 + rb] + bcL[m0 + rb], 0.f);
                *(h4_t*)(Hsw + ((size_t)(t * 4 + aa) * 32 + li) * 8 + 4 * q2) = v4;
            }
        }
        __syncthreads();

        // ---------------- gemm3: upd = W3*H (K split 4 waves) -------------
        fx16 acc3[3];
#pragma unroll
        for (int mt = 0; mt < 3; ++mt)
#pragma unroll
            for (int r = 0; r < 16; ++r) acc3[mt][r] = 0.f;
#pragma unroll
        for (int k2 = 0; k2 < 8; ++k2) {
            const int ks2 = w * 8 + k2;
            const h8_t bf = *(const h8_t*)(Hsw +
                ((size_t)(ks2 * 2 + q2) * 32 + li) * 8);
#pragma unroll
            for (int mt = 0; mt < 3; ++mt)
                acc3[mt] = __builtin_amdgcn_mfma_f32_32x32x16_f16(
                    w3r[k2][mt], bf, acc3[mt], 0, 0, 0);
        }
        __syncthreads();   // all Hsw/msT reads done before redT overlay

        // cross-wave K reduction via LDS
#pragma unroll
        for (int mt = 0; mt < 3; ++mt)
#pragma unroll
            for (int aa = 0; aa < 4; ++aa) {
                float4 v;
                v.x = acc3[mt][aa * 4 + 0]; v.y = acc3[mt][aa * 4 + 1];
                v.z = acc3[mt][aa * 4 + 2]; v.w = acc3[mt][aa * 4 + 3];
                *(float4*)(redT + (((w * 3 + mt) * 4 + aa) * 256 + lane * 4)) = v;
            }
        __syncthreads();

        // ---------------- state epilogue: U = M + upd + b3 ----------------
        if (w < 3) {
            const int mt = w;
            const float lv = livef[32 + li];
#pragma unroll
            for (int aa = 0; aa < 4; ++aa) {
                const float4 s0 = *(float4*)(redT + (((0 * 3 + mt) * 4 + aa) * 256 + lane * 4));
                const float4 s1 = *(float4*)(redT + (((1 * 3 + mt) * 4 + aa) * 256 + lane * 4));
                const float4 s2 = *(float4*)(redT + (((2 * 3 + mt) * 4 + aa) * 256 + lane * 4));
                const float4 s3 = *(float4*)(redT + (((3 * 3 + mt) * 4 + aa) * 256 + lane * 4));
                const float t4[4] = {s0.x + s1.x + s2.x + s3.x,
                                     s0.y + s1.y + s2.y + s3.y,
                                     s0.z + s1.z + s2.z + s3.z,
                                     s0.w + s1.w + s2.w + s3.w};
#pragma unroll
                for (int rb = 0; rb < 4; ++rb) {
                    const int c = mt * 32 + rb + 8 * aa + 4 * q2;
                    if (c < 80) {
                        const size_t idx = (size_t)c * NPIX + nbg;
                        const float base = (s == 0)
                            ? ((y0 == 16 && li == 16) ? (c ? z[b * 100 + c - 1] : 1.f) : 0.f)
                            : Uprev[idx] * lv;
                        Ucur[idx] = base + t4[rb] + b3L[c];
                    }
                }
            }
        }

        gbar(flags, go, s + 1);
    }
}

// ---------------------------------------------------------------------------
extern "C" void kernel_launch(void* const* d_in, const int* in_sizes, int n_in,
                              void* d_out, int out_size, void* d_ws, size_t ws_size,
                              hipStream_t stream)
{
    const float* z  = (const float*)d_in[0];
    const float* W1 = (const float*)d_in[1];   // 512 x 720
    const float* b1 = (const float*)d_in[2];
    const float* W2 = (const float*)d_in[3];   // 512 x 512
    const float* b2 = (const float*)d_in[4];
    const float* W3 = (const float*)d_in[5];   // 80 x 512
    const float* b3 = (const float*)d_in[6];

    char* ws = (char*)d_ws;
    float* U0    = (float*)ws;  ws += (size_t)80 * NPIX * 4;
    float* U1    = (float*)ws;  ws += (size_t)80 * NPIX * 4;
    float* Ma0   = (float*)ws;  ws += NPIX * 4;
    float* Ma1   = (float*)ws;  ws += NPIX * 4;
    float* bc    = (float*)ws;  ws += 512 * 4;
    float* Wc    = (float*)ws;  ws += (size_t)512 * 720 * 4;
    f16*   Wcsw2 = (f16*)ws;   ws += (size_t)45 * 16 * 64 * 8 * 2;
    f16*   W3sw2 = (f16*)ws;   ws += (size_t)32 * 3 * 64 * 8 * 2;
    int*   bar   = (int*)ws;   ws += 2048;

    hipMemsetAsync(bar, 0, 2048, stream);
    wc_gemm<<<dim3(3, 128), 256, 0, stream>>>(W1, W2, Wc);
    bc_k<<<2, 256, 0, stream>>>(W2, b1, b2, bc);
    swz_wc2<<<180, 256, 0, stream>>>(Wc, Wcsw2);
    swz_w32<<<24, 256, 0, stream>>>(W3, W3sw2);

    ca3<<<NBLK, 256, 0, stream>>>(z, b3, Wcsw2, W3sw2, bc,
                                  U0, U1, Ma0, Ma1,
                                  (float*)d_out, bar);
}

// Round 7
// 2765.606 us; speedup vs baseline: 3.5301x; 2.6982x over previous
//
#include <hip/hip_runtime.h>

// CAGenerator: 64-step neural CA — 2 dispatches/step, fence-free.
// Folded: Wc = W2@W1 (512x720), bc = W2@b1+b2 (no relu between conv3x3 and
// the first 1x1). mask = uniform()<1.0 is always true -> no RNG.
// Per step:
//   K1 (grid 64x4): H = relu(Wc * im2col(S)) for a 4-row band x 128 channels.
//      im2col built on-the-fly from a 6-row masked-state LDS tile using the
//      permuted-K layout kp = tap*80+ci (8-elem fragment run = 8 consecutive
//      channels at one (dy,dx) tap -> one ds_read_b128). H stored in
//      K2-fragment-ready octet layout: H[(ch>>3)*NPIX*8 + px*8 + (ch&7)].
//   K2 (grid 64): upd = W3*H (wave = row, full K per wave); halo alpha rows
//      via VALU dot; pre/post living masks; Snew = (S + upd + b3) * live.
// No persistent kernel, no grid barriers, no device fences -> L2 stays warm
// within each dispatch; runtime handles inter-dispatch coherence.

#define NPIX 8192
#define T_ALIVE 0.01f

typedef _Float16 f16;
typedef __attribute__((ext_vector_type(8)))  _Float16 h8_t;
typedef __attribute__((ext_vector_type(4)))  _Float16 h4_t;
typedef __attribute__((ext_vector_type(16))) float    fx16;

// ---------------------------------------------------------------------------
// Prep kernels (verified R4-R6)
// ---------------------------------------------------------------------------
__global__ __launch_bounds__(256) void wc_gemm(
    const float* __restrict__ W1, const float* __restrict__ W2,
    float* __restrict__ Wc)
{
    const int k = blockIdx.x * 256 + threadIdx.x;
    const int by = blockIdx.y;
    if (k >= 720) return;
    float a0 = 0.f, a1 = 0.f, a2 = 0.f, a3 = 0.f;
    for (int h = 0; h < 512; ++h) {
        const float w1v = W1[h * 720 + k];
        a0 += W2[(by      ) * 512 + h] * w1v;
        a1 += W2[(by + 128) * 512 + h] * w1v;
        a2 += W2[(by + 256) * 512 + h] * w1v;
        a3 += W2[(by + 384) * 512 + h] * w1v;
    }
    Wc[(size_t)(by      ) * 720 + k] = a0;
    Wc[(size_t)(by + 128) * 720 + k] = a1;
    Wc[(size_t)(by + 256) * 720 + k] = a2;
    Wc[(size_t)(by + 384) * 720 + k] = a3;
}

__global__ __launch_bounds__(256) void bc_k(
    const float* __restrict__ W2, const float* __restrict__ b1,
    const float* __restrict__ b2, float* __restrict__ bc)
{
    const int m = blockIdx.x * 256 + threadIdx.x;
    if (m >= 512) return;
    float a = b2[m];
    for (int h = 0; h < 512; ++h) a += W2[m * 512 + h] * b1[h];
    bc[m] = a;
}

// 32x32x16 A-frags, K permuted (kp = tap*80+ci), 720 = 45*16 exactly.
__global__ __launch_bounds__(256) void swz_wc2(
    const float* __restrict__ Wc, f16* __restrict__ Wcsw2)
{
    const int idx = blockIdx.x * 256 + threadIdx.x;
    if (idx >= 45 * 16 * 64) return;
    const int lane = idx & 63;
    const int t = idx >> 6;
    const int mtg = t & 15, ks = t >> 4;
    const int m = mtg * 32 + (lane & 31);
    const int k0 = ks * 16 + (lane >> 5) * 8;
    h8_t v;
#pragma unroll
    for (int j = 0; j < 8; ++j) {
        const int kp = k0 + j;
        const int tap = kp / 80, ci = kp - tap * 80;
        v[j] = (f16)Wc[(size_t)m * 720 + ci * 9 + tap];
    }
    *(h8_t*)(Wcsw2 + (size_t)idx * 8) = v;
}

// 32x32x16 A-frags for W3 (80x512 padded to 96 rows).
__global__ __launch_bounds__(256) void swz_w32(
    const float* __restrict__ W3, f16* __restrict__ W3sw2)
{
    const int idx = blockIdx.x * 256 + threadIdx.x;
    if (idx >= 32 * 3 * 64) return;
    const int lane = idx & 63;
    const int t = idx >> 6;
    const int mt = t % 3, ks2 = t / 3;
    const int m = mt * 32 + (lane & 31);
    const int k0 = ks2 * 16 + (lane >> 5) * 8;
    h8_t v;
#pragma unroll
    for (int j = 0; j < 8; ++j)
        v[j] = (f16)((m < 80) ? W3[(size_t)m * 512 + k0 + j] : 0.f);
    *(h8_t*)(W3sw2 + (size_t)idx * 8) = v;
}

__global__ __launch_bounds__(256) void seed_k(
    const float* __restrict__ z, float* __restrict__ S)
{
    const int idx = blockIdx.x * 256 + threadIdx.x;
    if (idx >= 640) return;
    const int b = idx / 80, c = idx - b * 80;
    const int n = b * 1024 + 16 * 32 + 16;
    S[(size_t)c * NPIX + n] = (c == 0) ? 1.f : z[b * 100 + (c - 1)];
}

// ---------------------------------------------------------------------------
// K1: H = relu(Wc * im2col(S)).  grid (64, 4): x = pixel band (img b = pb>>3,
// rows y0..y0+3, y0 = (pb&7)*4), y = mb (128-channel chunk).
// Wave w computes row y0+w (32 px) x 128 ch.  A-frags identical across the
// 4 waves -> L1-served.  H octet layout: H[(ch>>3)*NPIX*8 + px*8 + (ch&7)].
// ---------------------------------------------------------------------------
__global__ __launch_bounds__(256) void k1_gemmH(
    const float* __restrict__ S, const f16* __restrict__ Wcsw2,
    const float* __restrict__ bc, f16* __restrict__ H)
{
    __shared__ f16  msT[16320];     // 10 octets x (6 rows x 34 px) x 8 halfs
    __shared__ float bcL[128];

    const int tid = threadIdx.x;
    const int lane = tid & 63, w = tid >> 6;
    const int li = lane & 31, q2 = lane >> 5;
    const int pb = blockIdx.x, mb = blockIdx.y;
    const int b = pb >> 3, y0 = (pb & 7) * 4;
    const int gb = b * 1024;

    if (tid < 128) bcL[tid] = bc[mb * 128 + tid];
    // stage masked state (S is already masked) as fp16 octets, 6-row window
    for (int idx = tid; idx < 2040; idx += 256) {
        const int cc = idx / 204, p = idx - cc * 204;
        const int r = p / 34, xi = p - r * 34;
        const int gx = xi - 1, y = y0 - 1 + r;
        const bool inb = ((unsigned)y < 32u) & ((unsigned)gx < 32u);
        h8_t v;
#pragma unroll
        for (int j = 0; j < 8; ++j) {
            float fv = 0.f;
            if (inb) fv = S[(size_t)(cc * 8 + j) * NPIX + gb + y * 32 + gx];
            v[j] = (f16)fv;
        }
        *(h8_t*)(msT + (size_t)idx * 8) = v;
    }
    __syncthreads();

    int pxh[9];
#pragma unroll
    for (int t = 0; t < 9; ++t)
        pxh[t] = ((t / 3) * 34 + li + (t % 3)) * 8;
    const int wbase = w * 272;      // w * 34 * 8

    fx16 acc[4];
#pragma unroll
    for (int i = 0; i < 4; ++i)
#pragma unroll
        for (int r = 0; r < 16; ++r) acc[i][r] = 0.f;

    h8_t abuf[4][4];                // depth-4 prefetch ring
#pragma unroll
    for (int pk = 0; pk < 4; ++pk)
#pragma unroll
        for (int i = 0; i < 4; ++i)
            abuf[pk][i] = *(const h8_t*)(Wcsw2 +
                (((size_t)pk * 16 + (mb * 4 + i)) * 64 + lane) * 8);

#pragma unroll
    for (int ks = 0; ks < 45; ++ks) {
        const int o0 = 2 * ks, o1 = 2 * ks + 1;
        const int a0 = (o0 % 10) * 1632 + wbase + pxh[o0 / 10];
        const int a1 = (o1 % 10) * 1632 + wbase + pxh[o1 / 10];
        const h8_t bf = *(const h8_t*)(msT + (q2 ? a1 : a0));
        h8_t av[4];
#pragma unroll
        for (int i = 0; i < 4; ++i) av[i] = abuf[ks & 3][i];
        if (ks + 4 < 45) {
#pragma unroll
            for (int i = 0; i < 4; ++i)
                abuf[ks & 3][i] = *(const h8_t*)(Wcsw2 +
                    (((size_t)(ks + 4) * 16 + (mb * 4 + i)) * 64 + lane) * 8);
        }
#pragma unroll
        for (int i = 0; i < 4; ++i)
            acc[i] = __builtin_amdgcn_mfma_f32_32x32x16_f16(
                av[i], bf, acc[i], 0, 0, 0);
    }

    // epilogue: relu(acc + bc) -> H octet layout (coalesced h4 stores)
    const size_t px = (size_t)(gb + (y0 + w) * 32 + li);
#pragma unroll
    for (int i = 0; i < 4; ++i) {
#pragma unroll
        for (int aa = 0; aa < 4; ++aa) {
            const int chl = i * 32 + 8 * aa + 4 * q2;    // + mb*128 globally
            const int co = mb * 16 + i * 4 + aa;         // channel octet
            h4_t v4;
#pragma unroll
            for (int rb = 0; rb < 4; ++rb)
                v4[rb] = (f16)fmaxf(acc[i][aa * 4 + rb] + bcL[chl + rb], 0.f);
            *(h4_t*)(H + ((size_t)co * NPIX + px) * 8 + 4 * q2) = v4;
        }
    }
}

// ---------------------------------------------------------------------------
// K2: upd = W3*H; live mask; Snew = (Sold + upd + b3) * live.
// grid 64: img b = blk>>3, rows y0..y0+3 (y0 = (blk&7)*4). Wave w = row y0+w.
// Halo alpha rows (y0-1, y0+4) via VALU dot of W3 row 0 with H.
// ---------------------------------------------------------------------------
__global__ __launch_bounds__(256) void k2_update(
    const f16* __restrict__ H, const f16* __restrict__ W3sw2,
    const float* __restrict__ W3, const float* __restrict__ b3,
    const float* __restrict__ Sold, float* __restrict__ Snew)
{
    __shared__ float w3r0[512];
    __shared__ float b3L[80];
    __shared__ float alphaN[192];   // 6 rows x 32 (y0-1 .. y0+4)
    __shared__ float alphaO[192];
    __shared__ float redH[256];
    __shared__ float liveL[128];

    const int tid = threadIdx.x;
    const int lane = tid & 63, w = tid >> 6;
    const int li = lane & 31, q2 = lane >> 5;
    const int blk = blockIdx.x;
    const int b = blk >> 3, y0 = (blk & 7) * 4;
    const int gb = b * 1024;

    for (int i = tid; i < 512; i += 256) w3r0[i] = W3[i];   // W3[0][k]
    if (tid < 80) b3L[tid] = b3[tid];
    if (tid < 192) {
        const int r = tid >> 5, x = tid & 31, y = y0 - 1 + r;
        alphaO[tid] = ((unsigned)y < 32u) ? Sold[gb + y * 32 + x] : -1e30f;
    }
    __syncthreads();

    // MFMA: 96(pad) x 32 px, K = 512
    const size_t px = (size_t)(gb + (y0 + w) * 32 + li);
    fx16 acc3[3];
#pragma unroll
    for (int mt = 0; mt < 3; ++mt)
#pragma unroll
        for (int r = 0; r < 16; ++r) acc3[mt][r] = 0.f;
#pragma unroll
    for (int ks2 = 0; ks2 < 32; ++ks2) {
        const h8_t bf = *(const h8_t*)(H + ((size_t)(ks2 * 2 + q2) * NPIX + px) * 8);
#pragma unroll
        for (int mt = 0; mt < 3; ++mt) {
            const h8_t a = *(const h8_t*)(W3sw2 +
                (((size_t)ks2 * 3 + mt) * 64 + lane) * 8);
            acc3[mt] = __builtin_amdgcn_mfma_f32_32x32x16_f16(a, bf, acc3[mt], 0, 0, 0);
        }
    }

    // own-row alpha_new: ch 0 lives in acc3[0][0] at lanes q2==0
    if (lane < 32)
        alphaN[(w + 1) * 32 + li] = alphaO[(w + 1) * 32 + li] + acc3[0][0] + b3L[0];

    // halo alpha_new rows (r=0: y0-1, r=5: y0+4) via dot, 4 threads/px
    {
        const int ph = tid >> 2, part = tid & 3;
        const int r = (ph < 32) ? 0 : 5;
        const int x = ph & 31;
        const int y = y0 - 1 + r;
        float partial = 0.f;
        if ((unsigned)y < 32u) {
            const size_t pg = (size_t)(gb + y * 32 + x);
            for (int co = part * 16; co < part * 16 + 16; ++co) {
                const h8_t hv = *(const h8_t*)(H + ((size_t)co * NPIX + pg) * 8);
#pragma unroll
                for (int j = 0; j < 8; ++j)
                    partial += (float)hv[j] * w3r0[co * 8 + j];
            }
        }
        redH[tid] = partial;
    }
    __syncthreads();
    if (tid < 64) {
        const int r = (tid < 32) ? 0 : 5;
        const int x = tid & 31;
        const int y = y0 - 1 + r;
        float aN = -1e30f;
        if ((unsigned)y < 32u)
            aN = alphaO[r * 32 + x] + redH[tid * 4] + redH[tid * 4 + 1]
               + redH[tid * 4 + 2] + redH[tid * 4 + 3] + b3L[0];
        alphaN[r * 32 + x] = aN;
    }
    __syncthreads();

    // live mask for own 4 rows
    if (tid < 128) {
        const int r = (tid >> 5) + 1, x = tid & 31;
        float mN = -1e30f, mO = -1e30f;
#pragma unroll
        for (int dy = -1; dy <= 1; ++dy)
#pragma unroll
            for (int dx = -1; dx <= 1; ++dx) {
                const int xx = x + dx;
                if ((unsigned)xx < 32u) {
                    mN = fmaxf(mN, alphaN[(r + dy) * 32 + xx]);
                    mO = fmaxf(mO, alphaO[(r + dy) * 32 + xx]);
                }
            }
        liveL[tid] = (mN > T_ALIVE && mO > T_ALIVE) ? 1.f : 0.f;
    }
    __syncthreads();

    // epilogue: Snew = (Sold + upd + b3) * live
    const float lv = liveL[w * 32 + li];
#pragma unroll
    for (int mt = 0; mt < 3; ++mt)
#pragma unroll
        for (int aa = 0; aa < 4; ++aa)
#pragma unroll
            for (int rb = 0; rb < 4; ++rb) {
                const int ch = mt * 32 + rb + 8 * aa + 4 * q2;
                if (ch < 80) {
                    const size_t idx = (size_t)ch * NPIX + px;
                    Snew[idx] = (Sold[idx] + acc3[mt][aa * 4 + rb] + b3L[ch]) * lv;
                }
            }
}

// ---------------------------------------------------------------------------
extern "C" void kernel_launch(void* const* d_in, const int* in_sizes, int n_in,
                              void* d_out, int out_size, void* d_ws, size_t ws_size,
                              hipStream_t stream)
{
    const float* z  = (const float*)d_in[0];
    const float* W1 = (const float*)d_in[1];   // 512 x 720
    const float* b1 = (const float*)d_in[2];
    const float* W2 = (const float*)d_in[3];   // 512 x 512
    const float* b2 = (const float*)d_in[4];
    const float* W3 = (const float*)d_in[5];   // 80 x 512
    const float* b3 = (const float*)d_in[6];

    char* ws = (char*)d_ws;
    float* S0    = (float*)ws;  ws += (size_t)80 * NPIX * 4;
    float* S1    = (float*)ws;  ws += (size_t)80 * NPIX * 4;
    float* bc    = (float*)ws;  ws += 512 * 4;
    float* Wc    = (float*)ws;  ws += (size_t)512 * 720 * 4;
    f16*   Wcsw2 = (f16*)ws;   ws += (size_t)45 * 16 * 64 * 8 * 2;
    f16*   W3sw2 = (f16*)ws;   ws += (size_t)32 * 3 * 64 * 8 * 2;
    f16*   H     = (f16*)ws;   ws += (size_t)64 * NPIX * 8 * 2;    // 8 MB

    hipMemsetAsync(S0, 0, (size_t)80 * NPIX * 4, stream);
    seed_k<<<3, 256, 0, stream>>>(z, S0);
    wc_gemm<<<dim3(3, 128), 256, 0, stream>>>(W1, W2, Wc);
    bc_k<<<2, 256, 0, stream>>>(W2, b1, b2, bc);
    swz_wc2<<<180, 256, 0, stream>>>(Wc, Wcsw2);
    swz_w32<<<24, 256, 0, stream>>>(W3, W3sw2);

    float* Scur = S0;
    float* Snxt = S1;
    for (int s = 0; s < 64; ++s) {
        k1_gemmH<<<dim3(64, 4), 256, 0, stream>>>(Scur, Wcsw2, bc, H);
        k2_update<<<64, 256, 0, stream>>>(H, W3sw2, W3, b3, Scur, Snxt);
        float* t = Scur; Scur = Snxt; Snxt = t;
    }

    // output = masked alpha plane = first 8192 floats of final state
    hipMemcpyAsync(d_out, Scur, NPIX * sizeof(float),
                   hipMemcpyDeviceToDevice, stream);
}

// Round 8
// 1975.169 us; speedup vs baseline: 4.9429x; 1.4002x over previous
//
#include <hip/hip_runtime.h>

// CAGenerator: 64-step neural CA — 2 dispatches/step, fence-free (R7 struct).
// R8: (1) masked state additionally kept PIXEL-MAJOR fp16 (Smf16[px][80]) so
// K1's LDS staging is contiguous 16B loads instead of 32KB-strided dwords;
// (2) once-per-launch Wc=W2@W1 fold now LDS-tiled (was 66us naive).
// Folded: Wc = W2@W1 (512x720), bc = W2@b1+b2 (no relu between conv3x3 and
// the first 1x1). mask = uniform()<1.0 is always true -> no RNG.
// Per step:
//   K1 (grid 64x4): H = relu(Wc * im2col(S)), im2col on-the-fly from a 6-row
//      masked-state LDS tile, permuted-K kp = tap*80+ci (fragment = one
//      ds_read_b128). H in K2-fragment octet layout H[(ch>>3)][px][8].
//   K2 (grid 64): upd = W3*H; halo alpha rows via VALU dot; live masks;
//      writes Sf32 (channel-major masked state) + Smf16 (pixel-major fp16).

#define NPIX 8192
#define T_ALIVE 0.01f

typedef _Float16 f16;
typedef __attribute__((ext_vector_type(8)))  _Float16 h8_t;
typedef __attribute__((ext_vector_type(4)))  _Float16 h4_t;
typedef __attribute__((ext_vector_type(16))) float    fx16;

// ---------------------------------------------------------------------------
// Prep: W2 transpose + tiled Wc fold + bc + swizzles + seed
// ---------------------------------------------------------------------------
__global__ __launch_bounds__(256) void tr512(
    const float* __restrict__ W2, float* __restrict__ W2T)
{
    __shared__ float t[32][33];
    const int bx = blockIdx.x & 15, by = blockIdx.x >> 4;
    const int x = threadIdx.x & 31, y8 = threadIdx.x >> 5;
#pragma unroll
    for (int r = 0; r < 32; r += 8)
        t[r + y8][x] = W2[(size_t)(by * 32 + r + y8) * 512 + bx * 32 + x];
    __syncthreads();
#pragma unroll
    for (int r = 0; r < 32; r += 8)
        W2T[(size_t)(bx * 32 + r + y8) * 512 + by * 32 + x] = t[x][r + y8];
}

// Wc[m][n] = sum_k W2T[k][m] * W1[k][n]; M=512, N=720 (edge-guarded), K=512.
__global__ __launch_bounds__(256) void wc_tiled(
    const float* __restrict__ W2T, const float* __restrict__ W1,
    float* __restrict__ Wc)
{
    __shared__ float As[16][64];
    __shared__ float Bs[16][64];
    const int tid = threadIdx.x;
    const int tx = tid & 15, ty = tid >> 4;
    const int m0 = blockIdx.y * 64, n0 = blockIdx.x * 64;
    float acc[4][4];
#pragma unroll
    for (int i = 0; i < 4; ++i)
#pragma unroll
        for (int j = 0; j < 4; ++j) acc[i][j] = 0.f;
    const int la = tid * 4, lak = la >> 6, lam = la & 63;

    for (int k0 = 0; k0 < 512; k0 += 16) {
        *(float4*)&As[lak][lam] =
            *(const float4*)(W2T + (size_t)(k0 + lak) * 512 + m0 + lam);
        float4 bv;
        if (n0 + 64 <= 720) {
            bv = *(const float4*)(W1 + (size_t)(k0 + lak) * 720 + n0 + lam);
        } else {
            const float* src = W1 + (size_t)(k0 + lak) * 720 + n0 + lam;
            bv.x = (n0 + lam + 0 < 720) ? src[0] : 0.f;
            bv.y = (n0 + lam + 1 < 720) ? src[1] : 0.f;
            bv.z = (n0 + lam + 2 < 720) ? src[2] : 0.f;
            bv.w = (n0 + lam + 3 < 720) ? src[3] : 0.f;
        }
        *(float4*)&Bs[lak][lam] = bv;
        __syncthreads();
#pragma unroll
        for (int kk = 0; kk < 16; ++kk) {
            float4 a4 = *(const float4*)&As[kk][ty * 4];
            float4 b4 = *(const float4*)&Bs[kk][tx * 4];
            float av[4] = {a4.x, a4.y, a4.z, a4.w};
            float bvv[4] = {b4.x, b4.y, b4.z, b4.w};
#pragma unroll
            for (int i = 0; i < 4; ++i)
#pragma unroll
                for (int j = 0; j < 4; ++j)
                    acc[i][j] = fmaf(av[i], bvv[j], acc[i][j]);
        }
        __syncthreads();
    }
#pragma unroll
    for (int i = 0; i < 4; ++i) {
        const int m = m0 + ty * 4 + i;
#pragma unroll
        for (int j = 0; j < 4; ++j) {
            const int n = n0 + tx * 4 + j;
            if (n < 720) Wc[(size_t)m * 720 + n] = acc[i][j];
        }
    }
}

__global__ __launch_bounds__(256) void bc_k(
    const float* __restrict__ W2, const float* __restrict__ b1,
    const float* __restrict__ b2, float* __restrict__ bc)
{
    const int m = blockIdx.x * 256 + threadIdx.x;
    if (m >= 512) return;
    float a = b2[m];
    for (int h = 0; h < 512; ++h) a += W2[m * 512 + h] * b1[h];
    bc[m] = a;
}

// 32x32x16 A-frags, K permuted (kp = tap*80+ci), 720 = 45*16 exactly.
__global__ __launch_bounds__(256) void swz_wc2(
    const float* __restrict__ Wc, f16* __restrict__ Wcsw2)
{
    const int idx = blockIdx.x * 256 + threadIdx.x;
    if (idx >= 45 * 16 * 64) return;
    const int lane = idx & 63;
    const int t = idx >> 6;
    const int mtg = t & 15, ks = t >> 4;
    const int m = mtg * 32 + (lane & 31);
    const int k0 = ks * 16 + (lane >> 5) * 8;
    h8_t v;
#pragma unroll
    for (int j = 0; j < 8; ++j) {
        const int kp = k0 + j;
        const int tap = kp / 80, ci = kp - tap * 80;
        v[j] = (f16)Wc[(size_t)m * 720 + ci * 9 + tap];
    }
    *(h8_t*)(Wcsw2 + (size_t)idx * 8) = v;
}

// 32x32x16 A-frags for W3 (80x512 padded to 96 rows).
__global__ __launch_bounds__(256) void swz_w32(
    const float* __restrict__ W3, f16* __restrict__ W3sw2)
{
    const int idx = blockIdx.x * 256 + threadIdx.x;
    if (idx >= 32 * 3 * 64) return;
    const int lane = idx & 63;
    const int t = idx >> 6;
    const int mt = t % 3, ks2 = t / 3;
    const int m = mt * 32 + (lane & 31);
    const int k0 = ks2 * 16 + (lane >> 5) * 8;
    h8_t v;
#pragma unroll
    for (int j = 0; j < 8; ++j)
        v[j] = (f16)((m < 80) ? W3[(size_t)m * 512 + k0 + j] : 0.f);
    *(h8_t*)(W3sw2 + (size_t)idx * 8) = v;
}

__global__ __launch_bounds__(256) void seed_k(
    const float* __restrict__ z, float* __restrict__ Sf32,
    f16* __restrict__ Smf16)
{
    const int idx = blockIdx.x * 256 + threadIdx.x;
    if (idx >= 640) return;
    const int b = idx / 80, c = idx - b * 80;
    const int n = b * 1024 + 16 * 32 + 16;
    const float v = (c == 0) ? 1.f : z[b * 100 + (c - 1)];
    Sf32[(size_t)c * NPIX + n] = v;
    Smf16[(size_t)n * 80 + c] = (f16)v;
}

// ---------------------------------------------------------------------------
// K1: H = relu(Wc * im2col(S)).  grid (64, 4): x = pixel band (img b = pb>>3,
// rows y0..y0+3), y = mb (128-channel chunk). Wave w = row y0+w (32 px).
// Staging reads Smf16 pixel-major (contiguous 16B octets).
// ---------------------------------------------------------------------------
__global__ __launch_bounds__(256) void k1_gemmH(
    const f16* __restrict__ Smf16, const f16* __restrict__ Wcsw2,
    const float* __restrict__ bc, f16* __restrict__ H)
{
    __shared__ f16  msT[16320];     // 10 octets x (6 rows x 34 px) x 8 halfs
    __shared__ float bcL[128];

    const int tid = threadIdx.x;
    const int lane = tid & 63, w = tid >> 6;
    const int li = lane & 31, q2 = lane >> 5;
    const int pb = blockIdx.x, mb = blockIdx.y;
    const int b = pb >> 3, y0 = (pb & 7) * 4;
    const int gb = b * 1024;

    if (tid < 128) bcL[tid] = bc[mb * 128 + tid];
    // stage masked state from pixel-major fp16 (contiguous 16B per (px,cc))
    for (int idx = tid; idx < 2040; idx += 256) {
        const int p = idx / 10, cc = idx - p * 10;
        const int r = p / 34, xi = p - r * 34;
        const int gx = xi - 1, y = y0 - 1 + r;
        h8_t v;
        if (((unsigned)y < 32u) & ((unsigned)gx < 32u)) {
            v = *(const h8_t*)(Smf16 + (size_t)(gb + y * 32 + gx) * 80 + cc * 8);
        } else {
#pragma unroll
            for (int j = 0; j < 8; ++j) v[j] = (f16)0.f;
        }
        *(h8_t*)(msT + (size_t)(cc * 204 + p) * 8) = v;
    }
    __syncthreads();

    int pxh[9];
#pragma unroll
    for (int t = 0; t < 9; ++t)
        pxh[t] = ((t / 3) * 34 + li + (t % 3)) * 8;
    const int wbase = w * 272;      // w * 34 * 8

    fx16 acc[4];
#pragma unroll
    for (int i = 0; i < 4; ++i)
#pragma unroll
        for (int r = 0; r < 16; ++r) acc[i][r] = 0.f;

    h8_t abuf[4][4];                // depth-4 prefetch ring
#pragma unroll
    for (int pk = 0; pk < 4; ++pk)
#pragma unroll
        for (int i = 0; i < 4; ++i)
            abuf[pk][i] = *(const h8_t*)(Wcsw2 +
                (((size_t)pk * 16 + (mb * 4 + i)) * 64 + lane) * 8);

#pragma unroll
    for (int ks = 0; ks < 45; ++ks) {
        const int o0 = 2 * ks, o1 = 2 * ks + 1;
        const int a0 = (o0 % 10) * 1632 + wbase + pxh[o0 / 10];
        const int a1 = (o1 % 10) * 1632 + wbase + pxh[o1 / 10];
        const h8_t bf = *(const h8_t*)(msT + (q2 ? a1 : a0));
        h8_t av[4];
#pragma unroll
        for (int i = 0; i < 4; ++i) av[i] = abuf[ks & 3][i];
        if (ks + 4 < 45) {
#pragma unroll
            for (int i = 0; i < 4; ++i)
                abuf[ks & 3][i] = *(const h8_t*)(Wcsw2 +
                    (((size_t)(ks + 4) * 16 + (mb * 4 + i)) * 64 + lane) * 8);
        }
#pragma unroll
        for (int i = 0; i < 4; ++i)
            acc[i] = __builtin_amdgcn_mfma_f32_32x32x16_f16(
                av[i], bf, acc[i], 0, 0, 0);
    }

    // epilogue: relu(acc + bc) -> H octet layout (coalesced h4 stores)
    const size_t px = (size_t)(gb + (y0 + w) * 32 + li);
#pragma unroll
    for (int i = 0; i < 4; ++i) {
#pragma unroll
        for (int aa = 0; aa < 4; ++aa) {
            const int chl = i * 32 + 8 * aa + 4 * q2;
            const int co = mb * 16 + i * 4 + aa;
            h4_t v4;
#pragma unroll
            for (int rb = 0; rb < 4; ++rb)
                v4[rb] = (f16)fmaxf(acc[i][aa * 4 + rb] + bcL[chl + rb], 0.f);
            *(h4_t*)(H + ((size_t)co * NPIX + px) * 8 + 4 * q2) = v4;
        }
    }
}

// ---------------------------------------------------------------------------
// K2: upd = W3*H; live mask; writes Sf32 (masked, channel-major) + Smf16
// (masked, pixel-major fp16). grid 64: b = blk>>3, rows y0..y0+3.
// ---------------------------------------------------------------------------
__global__ __launch_bounds__(256) void k2_update(
    const f16* __restrict__ H, const f16* __restrict__ W3sw2,
    const float* __restrict__ W3, const float* __restrict__ b3,
    const float* __restrict__ Sold, float* __restrict__ Snew,
    f16* __restrict__ Smf16)
{
    __shared__ float w3r0[512];
    __shared__ float b3L[80];
    __shared__ float alphaN[192];   // 6 rows x 32 (y0-1 .. y0+4)
    __shared__ float alphaO[192];
    __shared__ float redH[256];
    __shared__ float liveL[128];

    const int tid = threadIdx.x;
    const int lane = tid & 63, w = tid >> 6;
    const int li = lane & 31, q2 = lane >> 5;
    const int blk = blockIdx.x;
    const int b = blk >> 3, y0 = (blk & 7) * 4;
    const int gb = b * 1024;

    for (int i = tid; i < 512; i += 256) w3r0[i] = W3[i];   // W3[0][k]
    if (tid < 80) b3L[tid] = b3[tid];
    if (tid < 192) {
        const int r = tid >> 5, x = tid & 31, y = y0 - 1 + r;
        alphaO[tid] = ((unsigned)y < 32u) ? Sold[gb + y * 32 + x] : -1e30f;
    }
    __syncthreads();

    // MFMA: 96(pad) x 32 px, K = 512
    const size_t px = (size_t)(gb + (y0 + w) * 32 + li);
    fx16 acc3[3];
#pragma unroll
    for (int mt = 0; mt < 3; ++mt)
#pragma unroll
        for (int r = 0; r < 16; ++r) acc3[mt][r] = 0.f;
#pragma unroll
    for (int ks2 = 0; ks2 < 32; ++ks2) {
        const h8_t bf = *(const h8_t*)(H + ((size_t)(ks2 * 2 + q2) * NPIX + px) * 8);
#pragma unroll
        for (int mt = 0; mt < 3; ++mt) {
            const h8_t a = *(const h8_t*)(W3sw2 +
                (((size_t)ks2 * 3 + mt) * 64 + lane) * 8);
            acc3[mt] = __builtin_amdgcn_mfma_f32_32x32x16_f16(a, bf, acc3[mt], 0, 0, 0);
        }
    }

    // own-row alpha_new: ch 0 at acc3[0][0], lanes q2==0
    if (lane < 32)
        alphaN[(w + 1) * 32 + li] = alphaO[(w + 1) * 32 + li] + acc3[0][0] + b3L[0];

    // halo alpha_new rows (y0-1, y0+4) via dot, 4 threads/px
    {
        const int ph = tid >> 2, part = tid & 3;
        const int r = (ph < 32) ? 0 : 5;
        const int x = ph & 31;
        const int y = y0 - 1 + r;
        float partial = 0.f;
        if ((unsigned)y < 32u) {
            const size_t pg = (size_t)(gb + y * 32 + x);
            for (int co = part * 16; co < part * 16 + 16; ++co) {
                const h8_t hv = *(const h8_t*)(H + ((size_t)co * NPIX + pg) * 8);
#pragma unroll
                for (int j = 0; j < 8; ++j)
                    partial += (float)hv[j] * w3r0[co * 8 + j];
            }
        }
        redH[tid] = partial;
    }
    __syncthreads();
    if (tid < 64) {
        const int r = (tid < 32) ? 0 : 5;
        const int x = tid & 31;
        const int y = y0 - 1 + r;
        float aN = -1e30f;
        if ((unsigned)y < 32u)
            aN = alphaO[r * 32 + x] + redH[tid * 4] + redH[tid * 4 + 1]
               + redH[tid * 4 + 2] + redH[tid * 4 + 3] + b3L[0];
        alphaN[r * 32 + x] = aN;
    }
    __syncthreads();

    // live mask for own 4 rows
    if (tid < 128) {
        const int r = (tid >> 5) + 1, x = tid & 31;
        float mN = -1e30f, mO = -1e30f;
#pragma unroll
        for (int dy = -1; dy <= 1; ++dy)
#pragma unroll
            for (int dx = -1; dx <= 1; ++dx) {
                const int xx = x + dx;
                if ((unsigned)xx < 32u) {
                    mN = fmaxf(mN, alphaN[(r + dy) * 32 + xx]);
                    mO = fmaxf(mO, alphaO[(r + dy) * 32 + xx]);
                }
            }
        liveL[tid] = (mN > T_ALIVE && mO > T_ALIVE) ? 1.f : 0.f;
    }
    __syncthreads();

    // epilogue: masked next state -> Sf32 (channel-major) + Smf16 (px-major)
    const float lv = liveL[w * 32 + li];
#pragma unroll
    for (int mt = 0; mt < 3; ++mt)
#pragma unroll
        for (int aa = 0; aa < 4; ++aa) {
            const int ch0 = mt * 32 + 8 * aa + 4 * q2;
            if (ch0 + 3 < 80) {
                h4_t v4;
#pragma unroll
                for (int rb = 0; rb < 4; ++rb) {
                    const int ch = ch0 + rb;
                    const size_t idx = (size_t)ch * NPIX + px;
                    const float v =
                        (Sold[idx] + acc3[mt][aa * 4 + rb] + b3L[ch]) * lv;
                    Snew[idx] = v;
                    v4[rb] = (f16)v;
                }
                *(h4_t*)(Smf16 + px * 80 + ch0) = v4;
            }
        }
}

// ---------------------------------------------------------------------------
extern "C" void kernel_launch(void* const* d_in, const int* in_sizes, int n_in,
                              void* d_out, int out_size, void* d_ws, size_t ws_size,
                              hipStream_t stream)
{
    const float* z  = (const float*)d_in[0];
    const float* W1 = (const float*)d_in[1];   // 512 x 720
    const float* b1 = (const float*)d_in[2];
    const float* W2 = (const float*)d_in[3];   // 512 x 512
    const float* b2 = (const float*)d_in[4];
    const float* W3 = (const float*)d_in[5];   // 80 x 512
    const float* b3 = (const float*)d_in[6];

    char* ws = (char*)d_ws;
    float* S0    = (float*)ws;  ws += (size_t)80 * NPIX * 4;
    float* S1    = (float*)ws;  ws += (size_t)80 * NPIX * 4;
    f16*   Sm0   = (f16*)ws;   ws += (size_t)NPIX * 80 * 2;
    f16*   Sm1   = (f16*)ws;   ws += (size_t)NPIX * 80 * 2;
    float* bc    = (float*)ws;  ws += 512 * 4;
    float* Wc    = (float*)ws;  ws += (size_t)512 * 720 * 4;
    float* W2T   = (float*)ws;  ws += (size_t)512 * 512 * 4;
    f16*   Wcsw2 = (f16*)ws;   ws += (size_t)45 * 16 * 64 * 8 * 2;
    f16*   W3sw2 = (f16*)ws;   ws += (size_t)32 * 3 * 64 * 8 * 2;
    f16*   H     = (f16*)ws;   ws += (size_t)64 * NPIX * 8 * 2;    // 8 MB

    hipMemsetAsync(S0, 0, (size_t)80 * NPIX * 4, stream);
    hipMemsetAsync(Sm0, 0, (size_t)NPIX * 80 * 2, stream);
    seed_k<<<3, 256, 0, stream>>>(z, S0, Sm0);
    tr512<<<256, 256, 0, stream>>>(W2, W2T);
    wc_tiled<<<dim3(12, 8), 256, 0, stream>>>(W2T, W1, Wc);
    bc_k<<<2, 256, 0, stream>>>(W2, b1, b2, bc);
    swz_wc2<<<180, 256, 0, stream>>>(Wc, Wcsw2);
    swz_w32<<<24, 256, 0, stream>>>(W3, W3sw2);

    float* Scur = S0;  float* Snxt = S1;
    f16*   Mcur = Sm0; f16*   Mnxt = Sm1;
    for (int s = 0; s < 64; ++s) {
        k1_gemmH<<<dim3(64, 4), 256, 0, stream>>>(Mcur, Wcsw2, bc, H);
        k2_update<<<64, 256, 0, stream>>>(H, W3sw2, W3, b3, Scur, Snxt, Mnxt);
        float* t = Scur; Scur = Snxt; Snxt = t;
        f16*   m = Mcur; Mcur = Mnxt; Mnxt = m;
    }

    // output = masked alpha plane = first 8192 floats of final state
    hipMemcpyAsync(d_out, Scur, NPIX * sizeof(float),
                   hipMemcpyDeviceToDevice, stream);
}

// Round 9
// 1686.447 us; speedup vs baseline: 5.7891x; 1.1712x over previous
//
#include <hip/hip_runtime.h>

// CAGenerator: 64-step neural CA — 2 dispatches/step, fence-free.
// R9: (1) wc fold 32x32-tiled (368 blocks); (2) k1 split into 512 blocks
// (band x 64-ch chunk, 2 blocks/CU) for 2x latency hiding on the L2 weight
// stream; (3) k2 re-gridded to 256 blocks (1 row each), halo-row alpha via
// MFMA (mt=0) instead of serial VALU dot, wave-K-split + LDS reduce.
// Folded: Wc = W2@W1 (512x720), bc = W2@b1+b2 (no relu between conv3x3 and
// the first 1x1). mask = uniform()<1.0 is always true -> no RNG.
// State kept twice: Sf32 channel-major (k2 epilogue / output) and Smf16
// pixel-major fp16 (k1 staging reads contiguous 16B octets).
// K-permutation kp = tap*80+ci: fragment = one ds_read_b128 from msT.

#define NPIX 8192
#define T_ALIVE 0.01f

typedef _Float16 f16;
typedef __attribute__((ext_vector_type(8)))  _Float16 h8_t;
typedef __attribute__((ext_vector_type(4)))  _Float16 h4_t;
typedef __attribute__((ext_vector_type(16))) float    fx16;

// ---------------------------------------------------------------------------
// Prep
// ---------------------------------------------------------------------------
__global__ __launch_bounds__(256) void tr512(
    const float* __restrict__ W2, float* __restrict__ W2T)
{
    __shared__ float t[32][33];
    const int bx = blockIdx.x & 15, by = blockIdx.x >> 4;
    const int x = threadIdx.x & 31, y8 = threadIdx.x >> 5;
#pragma unroll
    for (int r = 0; r < 32; r += 8)
        t[r + y8][x] = W2[(size_t)(by * 32 + r + y8) * 512 + bx * 32 + x];
    __syncthreads();
#pragma unroll
    for (int r = 0; r < 32; r += 8)
        W2T[(size_t)(bx * 32 + r + y8) * 512 + by * 32 + x] = t[x][r + y8];
}

// Wc[m][n] = sum_k W2T[k][m]*W1[k][n]; 32x32 tiles, grid (23,16).
__global__ __launch_bounds__(256) void wc32(
    const float* __restrict__ W2T, const float* __restrict__ W1,
    float* __restrict__ Wc)
{
    __shared__ float As[16][32];
    __shared__ float Bs[16][32];
    const int tid = threadIdx.x;
    const int ty = tid >> 3, tx = tid & 7;
    const int m0 = blockIdx.y * 32, n0 = blockIdx.x * 32;
    float acc[4] = {0.f, 0.f, 0.f, 0.f};

    for (int k0 = 0; k0 < 512; k0 += 16) {
#pragma unroll
        for (int t = 0; t < 2; ++t) {
            const int idx = tid + t * 256;
            const int r = idx >> 5, c = idx & 31;
            As[r][c] = W2T[(size_t)(k0 + r) * 512 + m0 + c];
            const int n = n0 + c;
            Bs[r][c] = (n < 720) ? W1[(size_t)(k0 + r) * 720 + n] : 0.f;
        }
        __syncthreads();
#pragma unroll
        for (int kk = 0; kk < 16; ++kk) {
            const float a = As[kk][ty];
#pragma unroll
            for (int j = 0; j < 4; ++j)
                acc[j] = fmaf(a, Bs[kk][tx * 4 + j], acc[j]);
        }
        __syncthreads();
    }
    const int m = m0 + ty;
#pragma unroll
    for (int j = 0; j < 4; ++j) {
        const int n = n0 + tx * 4 + j;
        if (n < 720) Wc[(size_t)m * 720 + n] = acc[j];
    }
}

__global__ __launch_bounds__(256) void bc_k(
    const float* __restrict__ W2, const float* __restrict__ b1,
    const float* __restrict__ b2, float* __restrict__ bc)
{
    const int m = blockIdx.x * 256 + threadIdx.x;
    if (m >= 512) return;
    float a = b2[m];
    for (int h = 0; h < 512; ++h) a += W2[m * 512 + h] * b1[h];
    bc[m] = a;
}

// 32x32x16 A-frags, K permuted (kp = tap*80+ci), 720 = 45*16 exactly.
__global__ __launch_bounds__(256) void swz_wc2(
    const float* __restrict__ Wc, f16* __restrict__ Wcsw2)
{
    const int idx = blockIdx.x * 256 + threadIdx.x;
    if (idx >= 45 * 16 * 64) return;
    const int lane = idx & 63;
    const int t = idx >> 6;
    const int mtg = t & 15, ks = t >> 4;
    const int m = mtg * 32 + (lane & 31);
    const int k0 = ks * 16 + (lane >> 5) * 8;
    h8_t v;
#pragma unroll
    for (int j = 0; j < 8; ++j) {
        const int kp = k0 + j;
        const int tap = kp / 80, ci = kp - tap * 80;
        v[j] = (f16)Wc[(size_t)m * 720 + ci * 9 + tap];
    }
    *(h8_t*)(Wcsw2 + (size_t)idx * 8) = v;
}

// 32x32x16 A-frags for W3 (80x512 padded to 96 rows).
__global__ __launch_bounds__(256) void swz_w32(
    const float* __restrict__ W3, f16* __restrict__ W3sw2)
{
    const int idx = blockIdx.x * 256 + threadIdx.x;
    if (idx >= 32 * 3 * 64) return;
    const int lane = idx & 63;
    const int t = idx >> 6;
    const int mt = t % 3, ks2 = t / 3;
    const int m = mt * 32 + (lane & 31);
    const int k0 = ks2 * 16 + (lane >> 5) * 8;
    h8_t v;
#pragma unroll
    for (int j = 0; j < 8; ++j)
        v[j] = (f16)((m < 80) ? W3[(size_t)m * 512 + k0 + j] : 0.f);
    *(h8_t*)(W3sw2 + (size_t)idx * 8) = v;
}

__global__ __launch_bounds__(256) void seed_k(
    const float* __restrict__ z, float* __restrict__ Sf32,
    f16* __restrict__ Smf16)
{
    const int idx = blockIdx.x * 256 + threadIdx.x;
    if (idx >= 640) return;
    const int b = idx / 80, c = idx - b * 80;
    const int n = b * 1024 + 16 * 32 + 16;
    const float v = (c == 0) ? 1.f : z[b * 100 + (c - 1)];
    Sf32[(size_t)c * NPIX + n] = v;
    Smf16[(size_t)n * 80 + c] = (f16)v;
}

// ---------------------------------------------------------------------------
// K1: H = relu(Wc * im2col(S)). grid (64, 8): x = pixel band (img b = pb>>3,
// rows y0..y0+3), y = mb (64-channel chunk). Wave w = row y0+w (32 px),
// 2 mt tiles per wave. 512 blocks -> 2 blocks/CU, 8 waves/CU.
// ---------------------------------------------------------------------------
__global__ __launch_bounds__(256) void k1_gemmH(
    const f16* __restrict__ Smf16, const f16* __restrict__ Wcsw2,
    const float* __restrict__ bc, f16* __restrict__ H)
{
    __shared__ f16  msT[16320];     // 10 octets x (6 rows x 34 px) x 8 halfs
    __shared__ float bcL[64];

    const int tid = threadIdx.x;
    const int lane = tid & 63, w = tid >> 6;
    const int li = lane & 31, q2 = lane >> 5;
    const int pb = blockIdx.x, mb = blockIdx.y;
    const int b = pb >> 3, y0 = (pb & 7) * 4;
    const int gb = b * 1024;

    if (tid < 64) bcL[tid] = bc[mb * 64 + tid];
    // stage masked state from pixel-major fp16 (contiguous 16B per (px,cc))
    for (int idx = tid; idx < 2040; idx += 256) {
        const int p = idx / 10, cc = idx - p * 10;
        const int r = p / 34, xi = p - r * 34;
        const int gx = xi - 1, y = y0 - 1 + r;
        h8_t v;
        if (((unsigned)y < 32u) & ((unsigned)gx < 32u)) {
            v = *(const h8_t*)(Smf16 + (size_t)(gb + y * 32 + gx) * 80 + cc * 8);
        } else {
#pragma unroll
            for (int j = 0; j < 8; ++j) v[j] = (f16)0.f;
        }
        *(h8_t*)(msT + (size_t)(cc * 204 + p) * 8) = v;
    }
    __syncthreads();

    int pxh[9];
#pragma unroll
    for (int t = 0; t < 9; ++t)
        pxh[t] = ((t / 3) * 34 + li + (t % 3)) * 8;
    const int wbase = w * 272;      // w * 34 * 8

    fx16 acc[2];
#pragma unroll
    for (int i = 0; i < 2; ++i)
#pragma unroll
        for (int r = 0; r < 16; ++r) acc[i][r] = 0.f;

    h8_t abuf[4][2];                // depth-4 prefetch ring
#pragma unroll
    for (int pk = 0; pk < 4; ++pk)
#pragma unroll
        for (int i = 0; i < 2; ++i)
            abuf[pk][i] = *(const h8_t*)(Wcsw2 +
                (((size_t)pk * 16 + (mb * 2 + i)) * 64 + lane) * 8);

#pragma unroll
    for (int ks = 0; ks < 45; ++ks) {
        const int o0 = 2 * ks, o1 = 2 * ks + 1;
        const int a0 = (o0 % 10) * 1632 + wbase + pxh[o0 / 10];
        const int a1 = (o1 % 10) * 1632 + wbase + pxh[o1 / 10];
        const h8_t bf = *(const h8_t*)(msT + (q2 ? a1 : a0));
        h8_t av[2];
#pragma unroll
        for (int i = 0; i < 2; ++i) av[i] = abuf[ks & 3][i];
        if (ks + 4 < 45) {
#pragma unroll
            for (int i = 0; i < 2; ++i)
                abuf[ks & 3][i] = *(const h8_t*)(Wcsw2 +
                    (((size_t)(ks + 4) * 16 + (mb * 2 + i)) * 64 + lane) * 8);
        }
#pragma unroll
        for (int i = 0; i < 2; ++i)
            acc[i] = __builtin_amdgcn_mfma_f32_32x32x16_f16(
                av[i], bf, acc[i], 0, 0, 0);
    }

    // epilogue: relu(acc + bc) -> H octet layout
    const size_t px = (size_t)(gb + (y0 + w) * 32 + li);
#pragma unroll
    for (int i = 0; i < 2; ++i) {
#pragma unroll
        for (int aa = 0; aa < 4; ++aa) {
            const int chl = i * 32 + 8 * aa + 4 * q2;
            const int co = mb * 8 + i * 4 + aa;
            h4_t v4;
#pragma unroll
            for (int rb = 0; rb < 4; ++rb)
                v4[rb] = (f16)fmaxf(acc[i][aa * 4 + rb] + bcL[chl + rb], 0.f);
            *(h4_t*)(H + ((size_t)co * NPIX + px) * 8 + 4 * q2) = v4;
        }
    }
}

// ---------------------------------------------------------------------------
// K2: upd = W3*H; live mask; Snew/Smf16 writes. grid 256: img b = blk>>5,
// row y = blk&31. Wave w covers K chunk [w*128,(w+1)*128): 24 MFMA own row +
// 16 MFMA (mt=0) for halo rows y+-1 (ch0 -> alphaN). LDS reduce over waves.
// ---------------------------------------------------------------------------
__global__ __launch_bounds__(256) void k2_update(
    const f16* __restrict__ H, const f16* __restrict__ W3sw2,
    const float* __restrict__ b3,
    const float* __restrict__ Sold, float* __restrict__ Snew,
    f16* __restrict__ Smf16)
{
    __shared__ float redT[12288];    // (w*3+mt)*4+aa)*256 + lane*4, 48 KB
    __shared__ float haloR[256];     // (w*2+rr)*32 + px
    __shared__ float alphaO3[96];
    __shared__ float alphaN3[96];
    __shared__ float b3L[80];
    __shared__ float livef[32];

    const int tid = threadIdx.x;
    const int lane = tid & 63, w = tid >> 6;
    const int li = lane & 31, q2 = lane >> 5;
    const int blk = blockIdx.x;
    const int b = blk >> 5, y = blk & 31;
    const int gb = b * 1024;
    const size_t px = (size_t)(gb + y * 32 + li);

    if (tid < 80) b3L[tid] = b3[tid];
    if (tid < 96) {
        const int r = tid >> 5, x = tid & 31, yy = y - 1 + r;
        alphaO3[tid] = ((unsigned)yy < 32u) ? Sold[gb + yy * 32 + x] : -1e30f;
    }

    // MFMA: own row (3 mt) + halo rows y-1,y+1 (mt=0 only, clamped addr)
    const int yU = (y > 0) ? y - 1 : 0;
    const int yD = (y < 31) ? y + 1 : 31;
    const size_t pxU = (size_t)(gb + yU * 32 + li);
    const size_t pxD = (size_t)(gb + yD * 32 + li);

    fx16 acc3[3], accH[2];
#pragma unroll
    for (int mt = 0; mt < 3; ++mt)
#pragma unroll
        for (int r = 0; r < 16; ++r) acc3[mt][r] = 0.f;
#pragma unroll
    for (int rr = 0; rr < 2; ++rr)
#pragma unroll
        for (int r = 0; r < 16; ++r) accH[rr][r] = 0.f;

#pragma unroll
    for (int k2 = 0; k2 < 8; ++k2) {
        const int ks2 = w * 8 + k2;
        const int co = ks2 * 2 + q2;
        const h8_t bf  = *(const h8_t*)(H + ((size_t)co * NPIX + px)  * 8);
        const h8_t bfU = *(const h8_t*)(H + ((size_t)co * NPIX + pxU) * 8);
        const h8_t bfD = *(const h8_t*)(H + ((size_t)co * NPIX + pxD) * 8);
        const h8_t a0 = *(const h8_t*)(W3sw2 + (((size_t)ks2 * 3 + 0) * 64 + lane) * 8);
        const h8_t a1 = *(const h8_t*)(W3sw2 + (((size_t)ks2 * 3 + 1) * 64 + lane) * 8);
        const h8_t a2 = *(const h8_t*)(W3sw2 + (((size_t)ks2 * 3 + 2) * 64 + lane) * 8);
        acc3[0] = __builtin_amdgcn_mfma_f32_32x32x16_f16(a0, bf,  acc3[0], 0, 0, 0);
        acc3[1] = __builtin_amdgcn_mfma_f32_32x32x16_f16(a1, bf,  acc3[1], 0, 0, 0);
        acc3[2] = __builtin_amdgcn_mfma_f32_32x32x16_f16(a2, bf,  acc3[2], 0, 0, 0);
        accH[0] = __builtin_amdgcn_mfma_f32_32x32x16_f16(a0, bfU, accH[0], 0, 0, 0);
        accH[1] = __builtin_amdgcn_mfma_f32_32x32x16_f16(a0, bfD, accH[1], 0, 0, 0);
    }

    // stash partials
#pragma unroll
    for (int mt = 0; mt < 3; ++mt)
#pragma unroll
        for (int aa = 0; aa < 4; ++aa) {
            float4 v;
            v.x = acc3[mt][aa * 4 + 0]; v.y = acc3[mt][aa * 4 + 1];
            v.z = acc3[mt][aa * 4 + 2]; v.w = acc3[mt][aa * 4 + 3];
            *(float4*)(redT + (((w * 3 + mt) * 4 + aa) * 256 + lane * 4)) = v;
        }
    if (lane < 32) {   // ch0 of halo rows: reg 0, q2==0 lanes
        haloR[(w * 2 + 0) * 32 + li] = accH[0][0];
        haloR[(w * 2 + 1) * 32 + li] = accH[1][0];
    }
    __syncthreads();

    // alphaN rows: own (r=1) from redT ch0; halo r=0/2 from haloR
    if (tid < 32) {
        float s = alphaO3[32 + tid] + b3L[0];
#pragma unroll
        for (int ww = 0; ww < 4; ++ww)
            s += redT[((ww * 3 + 0) * 4 + 0) * 256 + tid * 4];
        alphaN3[32 + tid] = s;
    } else if (tid < 96) {
        const int rr = (tid >> 5) - 1, x = tid & 31;   // rr 0->row y-1,1->y+1
        const int yy = y - 1 + 2 * rr;
        float aN = -1e30f;
        if ((unsigned)yy < 32u) {
            aN = alphaO3[2 * rr * 32 + x] + b3L[0];
#pragma unroll
            for (int ww = 0; ww < 4; ++ww)
                aN += haloR[(ww * 2 + rr) * 32 + x];
        }
        alphaN3[2 * rr * 32 + x] = aN;
    }
    __syncthreads();

    // live mask for own row
    if (tid < 32) {
        float mN = -1e30f, mO = -1e30f;
#pragma unroll
        for (int r = 0; r < 3; ++r)
#pragma unroll
            for (int dx = -1; dx <= 1; ++dx) {
                const int xx = tid + dx;
                if ((unsigned)xx < 32u) {
                    mN = fmaxf(mN, alphaN3[r * 32 + xx]);
                    mO = fmaxf(mO, alphaO3[r * 32 + xx]);
                }
            }
        livef[tid] = (mN > T_ALIVE && mO > T_ALIVE) ? 1.f : 0.f;
    }
    __syncthreads();

    // epilogue: waves 0..2 reduce + write Snew (ch-major) / Smf16 (px-major)
    if (w < 3) {
        const int mt = w;
        const float lv = livef[li];
#pragma unroll
        for (int aa = 0; aa < 4; ++aa) {
            const float4 s0 = *(float4*)(redT + (((0 * 3 + mt) * 4 + aa) * 256 + lane * 4));
            const float4 s1 = *(float4*)(redT + (((1 * 3 + mt) * 4 + aa) * 256 + lane * 4));
            const float4 s2 = *(float4*)(redT + (((2 * 3 + mt) * 4 + aa) * 256 + lane * 4));
            const float4 s3 = *(float4*)(redT + (((3 * 3 + mt) * 4 + aa) * 256 + lane * 4));
            const float t4[4] = {s0.x + s1.x + s2.x + s3.x,
                                 s0.y + s1.y + s2.y + s3.y,
                                 s0.z + s1.z + s2.z + s3.z,
                                 s0.w + s1.w + s2.w + s3.w};
            const int ch0 = mt * 32 + 8 * aa + 4 * q2;
            if (ch0 + 3 < 80) {
                h4_t v4;
#pragma unroll
                for (int rb = 0; rb < 4; ++rb) {
                    const int ch = ch0 + rb;
                    const size_t idx = (size_t)ch * NPIX + px;
                    const float v = (Sold[idx] + t4[rb] + b3L[ch]) * lv;
                    Snew[idx] = v;
                    v4[rb] = (f16)v;
                }
                *(h4_t*)(Smf16 + px * 80 + ch0) = v4;
            }
        }
    }
}

// ---------------------------------------------------------------------------
extern "C" void kernel_launch(void* const* d_in, const int* in_sizes, int n_in,
                              void* d_out, int out_size, void* d_ws, size_t ws_size,
                              hipStream_t stream)
{
    const float* z  = (const float*)d_in[0];
    const float* W1 = (const float*)d_in[1];   // 512 x 720
    const float* b1 = (const float*)d_in[2];
    const float* W2 = (const float*)d_in[3];   // 512 x 512
    const float* b2 = (const float*)d_in[4];
    const float* W3 = (const float*)d_in[5];   // 80 x 512
    const float* b3 = (const float*)d_in[6];

    char* ws = (char*)d_ws;
    float* S0    = (float*)ws;  ws += (size_t)80 * NPIX * 4;
    float* S1    = (float*)ws;  ws += (size_t)80 * NPIX * 4;
    f16*   Sm0   = (f16*)ws;   ws += (size_t)NPIX * 80 * 2;
    f16*   Sm1   = (f16*)ws;   ws += (size_t)NPIX * 80 * 2;
    float* bc    = (float*)ws;  ws += 512 * 4;
    float* Wc    = (float*)ws;  ws += (size_t)512 * 720 * 4;
    float* W2T   = (float*)ws;  ws += (size_t)512 * 512 * 4;
    f16*   Wcsw2 = (f16*)ws;   ws += (size_t)45 * 16 * 64 * 8 * 2;
    f16*   W3sw2 = (f16*)ws;   ws += (size_t)32 * 3 * 64 * 8 * 2;
    f16*   H     = (f16*)ws;   ws += (size_t)64 * NPIX * 8 * 2;    // 8 MB

    hipMemsetAsync(S0, 0, (size_t)80 * NPIX * 4, stream);
    hipMemsetAsync(Sm0, 0, (size_t)NPIX * 80 * 2, stream);
    seed_k<<<3, 256, 0, stream>>>(z, S0, Sm0);
    tr512<<<256, 256, 0, stream>>>(W2, W2T);
    wc32<<<dim3(23, 16), 256, 0, stream>>>(W2T, W1, Wc);
    bc_k<<<2, 256, 0, stream>>>(W2, b1, b2, bc);
    swz_wc2<<<180, 256, 0, stream>>>(Wc, Wcsw2);
    swz_w32<<<24, 256, 0, stream>>>(W3, W3sw2);

    float* Scur = S0;  float* Snxt = S1;
    f16*   Mcur = Sm0; f16*   Mnxt = Sm1;
    for (int s = 0; s < 64; ++s) {
        k1_gemmH<<<dim3(64, 8), 256, 0, stream>>>(Mcur, Wcsw2, bc, H);
        k2_update<<<256, 256, 0, stream>>>(H, W3sw2, b3, Scur, Snxt, Mnxt);
        float* t = Scur; Scur = Snxt; Snxt = t;
        f16*   m = Mcur; Mcur = Mnxt; Mnxt = m;
    }

    // output = masked alpha plane = first 8192 floats of final state
    hipMemcpyAsync(d_out, Scur, NPIX * sizeof(float),
                   hipMemcpyDeviceToDevice, stream);
}